// Round 1
// baseline (315.765 us; speedup 1.0000x reference)
//
#include <hip/hip_runtime.h>

#define NB 2
#define DD 480
#define HH 360
#define WD 32
#define CIN 16
#define COUT 32
#define EPSV 1e-5f
#define NEGS 0.01f

__global__ __launch_bounds__(256) void scatter_grid(const int* __restrict__ coords,
                                                    int* __restrict__ grid, int n) {
    int i = blockIdx.x * 256 + threadIdx.x;
    if (i >= n) return;
    int b = coords[i * 4 + 0];
    int z = coords[i * 4 + 1];
    int y = coords[i * 4 + 2];
    int x = coords[i * 4 + 3];
    grid[(((size_t)b * DD + z) * HH + y) * WD + x] = i;
}

// nbr133: offsets (0,dy,dx), k = (dy+1)*3 + (dx+1)
// nbr313: offsets (dz,0,dx), k = (dz+1)*3 + (dx+1)
__global__ __launch_bounds__(256) void build_nbr(const int* __restrict__ coords,
                                                 const int* __restrict__ grid,
                                                 int* __restrict__ nbr133,
                                                 int* __restrict__ nbr313, int n) {
    int i = blockIdx.x * 256 + threadIdx.x;
    if (i >= n) return;
    int b = coords[i * 4 + 0];
    int z = coords[i * 4 + 1];
    int y = coords[i * 4 + 2];
    int x = coords[i * 4 + 3];
    size_t base_b = (size_t)b * DD;
#pragma unroll
    for (int k = 0; k < 9; ++k) {
        int d0 = k / 3 - 1;  // dy for 133, dz for 313
        int dx = k % 3 - 1;
        int nx = x + dx;
        bool xok = (nx >= 0) && (nx < WD);
        // 133: (0, dy, dx)
        int ny = y + d0;
        int v1 = -1;
        if (xok && ny >= 0 && ny < HH)
            v1 = grid[((base_b + z) * HH + ny) * WD + nx];
        nbr133[(size_t)k * n + i] = v1;
        // 313: (dz, 0, dx)
        int nz = z + d0;
        int v2 = -1;
        if (xok && nz >= 0 && nz < DD)
            v2 = grid[((base_b + nz) * HH + y) * WD + nx];
        nbr313[(size_t)k * n + i] = v2;
    }
}

template <int CI, bool ADD>
__global__ __launch_bounds__(256) void conv_bn(const float* __restrict__ in,
                                               const int* __restrict__ nbr,
                                               const float* __restrict__ Wg,
                                               const float* __restrict__ gamma,
                                               const float* __restrict__ beta,
                                               const float* __restrict__ mean,
                                               const float* __restrict__ var,
                                               const float* __restrict__ res,
                                               float* __restrict__ out, int n) {
    __shared__ float Wl[9 * CI * COUT];
    __shared__ float sscale[COUT];
    __shared__ float sshift[COUT];
    int tid = threadIdx.x;
    for (int t = tid; t < 9 * CI * COUT; t += 256) Wl[t] = Wg[t];
    if (tid < COUT) {
        float g = gamma[tid], bt = beta[tid], m = mean[tid], v = var[tid];
        float s = g * rsqrtf(v + EPSV);
        sscale[tid] = s;
        sshift[tid] = bt - m * s;
    }
    __syncthreads();

    int i = blockIdx.x * 256 + tid;
    if (i >= n) return;

    float acc[COUT];
#pragma unroll
    for (int c = 0; c < COUT; ++c) acc[c] = 0.f;

#pragma unroll
    for (int k = 0; k < 9; ++k) {
        int j = nbr[(size_t)k * n + i];
        if (j < 0) continue;
        const float4* f4 = (const float4*)(in + (size_t)j * CI);
#pragma unroll
        for (int q = 0; q < CI / 4; ++q) {
            float4 v = f4[q];
            const float* w = &Wl[(k * CI + q * 4) * COUT];
#pragma unroll
            for (int c4 = 0; c4 < COUT / 4; ++c4) {
                float4 w0 = *(const float4*)&w[0 * COUT + c4 * 4];
                float4 w1 = *(const float4*)&w[1 * COUT + c4 * 4];
                float4 w2 = *(const float4*)&w[2 * COUT + c4 * 4];
                float4 w3 = *(const float4*)&w[3 * COUT + c4 * 4];
                acc[c4 * 4 + 0] += v.x * w0.x + v.y * w1.x + v.z * w2.x + v.w * w3.x;
                acc[c4 * 4 + 1] += v.x * w0.y + v.y * w1.y + v.z * w2.y + v.w * w3.y;
                acc[c4 * 4 + 2] += v.x * w0.z + v.y * w1.z + v.z * w2.z + v.w * w3.z;
                acc[c4 * 4 + 3] += v.x * w0.w + v.y * w1.w + v.z * w2.w + v.w * w3.w;
            }
        }
    }

#pragma unroll
    for (int c = 0; c < COUT; ++c) {
        float y = acc[c] * sscale[c] + sshift[c];
        y = (y >= 0.f) ? y : NEGS * y;
        if (ADD) y += res[(size_t)i * COUT + c];
        acc[c] = y;
    }
    float4* o = (float4*)(out + (size_t)i * COUT);
#pragma unroll
    for (int c4 = 0; c4 < COUT / 4; ++c4)
        o[c4] = make_float4(acc[4 * c4 + 0], acc[4 * c4 + 1], acc[4 * c4 + 2], acc[4 * c4 + 3]);
}

extern "C" void kernel_launch(void* const* d_in, const int* in_sizes, int n_in,
                              void* d_out, int out_size, void* d_ws, size_t ws_size,
                              hipStream_t stream) {
    const float* feats = (const float*)d_in[0];
    const int* coords  = (const int*)d_in[1];
    const float* W1    = (const float*)d_in[2];
    const float* W2    = (const float*)d_in[3];
    const float* W3    = (const float*)d_in[4];
    const float* W4    = (const float*)d_in[5];
    const float* gamma = (const float*)d_in[6];
    const float* beta  = (const float*)d_in[7];
    const float* mean  = (const float*)d_in[8];
    const float* var   = (const float*)d_in[9];

    int n = in_sizes[0] / CIN;  // 200000

    char* ws = (char*)d_ws;
    size_t nbrBytes  = (size_t)9 * n * sizeof(int);
    size_t featBytes = (size_t)n * COUT * sizeof(float);
    size_t gridBytes = (size_t)NB * DD * HH * WD * sizeof(int);

    int* nbr133 = (int*)ws;
    int* nbr313 = (int*)(ws + nbrBytes);
    char* fbase = ws + 2 * nbrBytes;
    float* s1 = (float*)fbase;                      // conv1 out
    float* s2 = (float*)(fbase + featBytes);        // shortcut
    float* r1 = (float*)(fbase + 2 * featBytes);    // conv3 out
    int* grid = (int*)fbase;  // overlaps s1/s2 region; grid is dead after build_nbr

    int nblk = (n + 255) / 256;

    hipMemsetAsync(grid, 0xFF, gridBytes, stream);
    scatter_grid<<<nblk, 256, 0, stream>>>(coords, grid, n);
    build_nbr<<<nblk, 256, 0, stream>>>(coords, grid, nbr133, nbr313, n);

    conv_bn<CIN, false><<<nblk, 256, 0, stream>>>(feats, nbr133, W1,
        gamma + 0 * COUT, beta + 0 * COUT, mean + 0 * COUT, var + 0 * COUT,
        nullptr, s1, n);
    conv_bn<COUT, false><<<nblk, 256, 0, stream>>>(s1, nbr313, W2,
        gamma + 1 * COUT, beta + 1 * COUT, mean + 1 * COUT, var + 1 * COUT,
        nullptr, s2, n);
    conv_bn<CIN, false><<<nblk, 256, 0, stream>>>(feats, nbr313, W3,
        gamma + 2 * COUT, beta + 2 * COUT, mean + 2 * COUT, var + 2 * COUT,
        nullptr, r1, n);
    conv_bn<COUT, true><<<nblk, 256, 0, stream>>>(r1, nbr133, W4,
        gamma + 3 * COUT, beta + 3 * COUT, mean + 3 * COUT, var + 3 * COUT,
        s2, (float*)d_out, n);
}